// Round 5
// baseline (793.614 us; speedup 1.0000x reference)
//
#include <hip/hip_runtime.h>

typedef __attribute__((ext_vector_type(8))) short short8;
typedef __attribute__((ext_vector_type(4))) float f32x4;
typedef unsigned short u16;

#define DEVI static __device__ __forceinline__

DEVI float bf2f(u16 u) {
    unsigned int x = ((unsigned int)u) << 16;
    float f;
    __builtin_memcpy(&f, &x, 4);
    return f;
}
DEVI u16 f2bf(float f) {
    unsigned int x;
    __builtin_memcpy(&x, &f, 4);
    unsigned int r = x + 0x7fffu + ((x >> 16) & 1u);
    return (u16)(r >> 16);
}

// ---------------- W f32 -> bf16 (with K padding to Kp) ----------------
__global__ __launch_bounds__(256) void convert_w_kernel(
    const float* __restrict__ wsrc, u16* __restrict__ wdst,
    int K, int Kp, long total_elems)
{
    long idx = (long)blockIdx.x * 256 + threadIdx.x;
    const long stride = (long)gridDim.x * 256;
    for (; idx < total_elems; idx += stride) {
        long rw = idx / Kp;
        int col = (int)(idx - rw * Kp);
        float v = (col < K) ? wsrc[rw * K + col] : 0.f;
        wdst[idx] = f2bf(v);
    }
}

// ------- row L2-normalize x0 (f32, K cols) -> bf16 (Kp cols, zero pad) -------
__global__ __launch_bounds__(256) void norm_x0_kernel(
    const float* __restrict__ x, u16* __restrict__ outp, int K, int Kp)
{
    const int row = blockIdx.x;
    const float* xr = x + (size_t)row * K;
    float ss = 0.f;
    for (int c = threadIdx.x; c < K; c += 256) { float v = xr[c]; ss += v * v; }
#pragma unroll
    for (int off = 32; off; off >>= 1) ss += __shfl_xor(ss, off);
    __shared__ float red[4];
    if ((threadIdx.x & 63) == 0) red[threadIdx.x >> 6] = ss;
    __syncthreads();
    const float tot = red[0] + red[1] + red[2] + red[3];
    const float scale = 1.f / (sqrtf(tot) + 1e-4f);
    u16* orow = outp + (size_t)row * Kp;
    for (int c = threadIdx.x; c < Kp; c += 256)
        orow[c] = f2bf(c < K ? xr[c] * scale : 0.f);
}

// ============ 256x256 GEMM: C = relu(A @ W^T + b), bf16 ============
// 8 waves (2M x 4N), BK=64, double-buffered 128 KiB LDS, T2 slot-swizzle,
// relaxed 5-barrier/K-tile phase schedule, counted vmcnt, setprio, T1 swizzle.
// Hazard guards: (a) per-tile rendezvous = each wave vmcnt-drains its own
// current-tile loads, then s_barrier -> collectively all data present;
// (b) lgkmcnt(0)+sched_barrier before each MFMA cluster (rule #18);
// (c) staging only 1 tile ahead; buf d's last read (ph2) is lgkm-drained
// before tile s+1 (which stages into d^1... d is restaged at s+2) per
// end-of-phase barriers. K % 64 == 0, NS >= 2.

#define MFMA_QUAD(qm_, qn_)                                                      \
    _Pragma("unroll") for (int i2_ = 0; i2_ < 4; ++i2_)                          \
    _Pragma("unroll") for (int j2_ = 0; j2_ < 2; ++j2_)                          \
    _Pragma("unroll") for (int kk_ = 0; kk_ < 2; ++kk_)                          \
        acc[(qm_) * 4 + i2_][(qn_) * 2 + j2_] =                                  \
            __builtin_amdgcn_mfma_f32_16x16x32_bf16(                             \
                a_[i2_][kk_], b_[(qn_) * 2 + j2_][kk_],                          \
                acc[(qm_) * 4 + i2_][(qn_) * 2 + j2_], 0, 0, 0)

// stage one half-tile (A+B, 2 loads) of K-step s_: ht_ = h*2+c
#define STAGE_HT(s_, ht_) do {                                                   \
    const int d_ = (s_) & 1;                                                     \
    const int h_ = (ht_) >> 1, c_ = (ht_) & 1;                                   \
    const size_t ko_ = (size_t)(s_) << 6;                                        \
    __builtin_amdgcn_global_load_lds(                                            \
        (const __attribute__((address_space(1))) void*)(pA + (size_t)(h_ * 128 + c_ * 64) * K + ko_), \
        (__attribute__((address_space(3))) void*)&ldsA[d_ * 16384 + h_ * 8192 + c_ * 4096 + w * 512], \
        16, 0, 0);                                                               \
    __builtin_amdgcn_global_load_lds(                                            \
        (const __attribute__((address_space(1))) void*)(pB + (size_t)(h_ * 128 + c_ * 64) * K + ko_), \
        (__attribute__((address_space(3))) void*)&ldsB[d_ * 16384 + h_ * 8192 + c_ * 4096 + w * 512], \
        16, 0, 0);                                                               \
} while (0)

__global__ __launch_bounds__(512, 2) void gemm256_8ph(
    const u16* __restrict__ A, const u16* __restrict__ W,
    const float* __restrict__ bias, u16* __restrict__ C,
    int N, int K)
{
    __shared__ __align__(16) u16 ldsA[2 * 2 * 128 * 64];  // [dbuf][half][128][64]
    __shared__ __align__(16) u16 ldsB[2 * 2 * 128 * 64];

    const int tid = threadIdx.x;
    const int lane = tid & 63;
    const int w = tid >> 6;               // wave 0..7
    const int wr = w >> 2, wc = w & 3;    // 2M x 4N wave grid
    const int rsel = lane & 15, hi = lane >> 4, lsw = lane & 7;

    // T1: XCD-aware bijective swizzle (grid % 8 == 0)
    int bid = blockIdx.x;
    const int cpx = gridDim.x >> 3;
    bid = (bid & 7) * cpx + (bid >> 3);
    const int ntn = N >> 8;
    const int tm = bid / ntn, tn = bid - tm * ntn;
    const size_t m0 = (size_t)tm << 8, n0 = (size_t)tn << 8;

    const int NS = K >> 6;

    // staging: thread t loads 16B; dest row (within half) = c*64 + (t>>3),
    // dest slot = t&7; source col-slot pre-swizzled (T2 involution).
    const int srow = tid >> 3;
    const int scol = ((tid & 7) ^ (srow & 7)) << 3;
    const u16* pA = A + (m0 + srow) * (size_t)K + scol;
    const u16* pB = W + (n0 + srow) * (size_t)K + scol;

    f32x4 acc[8][4] = {};
    short8 a_[4][2], b_[4][2];

    STAGE_HT(0, 0); STAGE_HT(0, 1); STAGE_HT(0, 2); STAGE_HT(0, 3);

    for (int s = 0; s < NS; ++s) {
        const int d = s & 1;
        const int dA = d * 16384 + wr * 8192;
        const int dB = d * 16384 + (wc >> 1) * 8192;
        const int brow = (wc & 1) * 64;
        const bool pf = (s + 1 < NS);

        // ---- phase 0: rendezvous, reads A0-3 + B0-1, MFMA q(0,0) ----
        if (pf) {
            STAGE_HT(s + 1, 0);
            asm volatile("s_waitcnt vmcnt(2)" ::: "memory");
        } else {
            asm volatile("s_waitcnt vmcnt(0)" ::: "memory");
        }
        __builtin_amdgcn_s_barrier();   // all waves drained own tile-s loads
#pragma unroll
        for (int i2 = 0; i2 < 4; ++i2)
#pragma unroll
            for (int kk = 0; kk < 2; ++kk)
                a_[i2][kk] = *(const short8*)&ldsA[dA + (i2 * 16 + rsel) * 64 + ((((kk << 2) + hi) ^ lsw) << 3)];
#pragma unroll
        for (int j2 = 0; j2 < 2; ++j2)
#pragma unroll
            for (int kk = 0; kk < 2; ++kk)
                b_[j2][kk] = *(const short8*)&ldsB[dB + (brow + j2 * 16 + rsel) * 64 + ((((kk << 2) + hi) ^ lsw) << 3)];
        asm volatile("s_waitcnt lgkmcnt(0)" ::: "memory");
        __builtin_amdgcn_sched_barrier(0);
        __builtin_amdgcn_s_setprio(1);
        MFMA_QUAD(0, 0);
        __builtin_amdgcn_s_setprio(0);
        __builtin_amdgcn_s_barrier();

        // ---- phase 1: reads B2-3, MFMA q(0,1) ----
        if (pf) STAGE_HT(s + 1, 1);
#pragma unroll
        for (int j2 = 2; j2 < 4; ++j2)
#pragma unroll
            for (int kk = 0; kk < 2; ++kk)
                b_[j2][kk] = *(const short8*)&ldsB[dB + (brow + j2 * 16 + rsel) * 64 + ((((kk << 2) + hi) ^ lsw) << 3)];
        asm volatile("s_waitcnt lgkmcnt(0)" ::: "memory");
        __builtin_amdgcn_sched_barrier(0);
        __builtin_amdgcn_s_setprio(1);
        MFMA_QUAD(0, 1);
        __builtin_amdgcn_s_setprio(0);
        __builtin_amdgcn_s_barrier();

        // ---- phase 2: reads A4-7, MFMA q(1,0) ----
        if (pf) STAGE_HT(s + 1, 2);
#pragma unroll
        for (int i2 = 0; i2 < 4; ++i2)
#pragma unroll
            for (int kk = 0; kk < 2; ++kk)
                a_[i2][kk] = *(const short8*)&ldsA[dA + ((i2 + 4) * 16 + rsel) * 64 + ((((kk << 2) + hi) ^ lsw) << 3)];
        asm volatile("s_waitcnt lgkmcnt(0)" ::: "memory");
        __builtin_amdgcn_sched_barrier(0);
        __builtin_amdgcn_s_setprio(1);
        MFMA_QUAD(1, 0);
        __builtin_amdgcn_s_setprio(0);
        __builtin_amdgcn_s_barrier();

        // ---- phase 3: MFMA q(1,1) ----
        if (pf) STAGE_HT(s + 1, 3);
        __builtin_amdgcn_s_setprio(1);
        MFMA_QUAD(1, 1);
        __builtin_amdgcn_s_setprio(0);
        __builtin_amdgcn_s_barrier();
    }

    // ---- epilogue: bias + relu, repack via own 16KB LDS region, coalesced store ----
    u16* ep = (w < 4) ? &ldsA[w * 8192] : &ldsB[(w - 4) * 8192];
#pragma unroll
    for (int j = 0; j < 4; ++j) {
        const float bv = bias[n0 + wc * 64 + j * 16 + rsel];
        const int slot = j * 2 + (rsel >> 3);   // col>>3
        const int cb = rsel & 7;                // col&7
#pragma unroll
        for (int i = 0; i < 8; ++i) {
#pragma unroll
            for (int rg = 0; rg < 4; ++rg) {
                const int row = i * 16 + hi * 4 + rg;
                float v = acc[i][j][rg] + bv;
                v = v > 0.f ? v : 0.f;
                ep[row * 64 + ((slot ^ (row & 7)) << 3) + cb] = f2bf(v);
            }
        }
    }
    asm volatile("s_waitcnt lgkmcnt(0)" ::: "memory");  // own writes drained (wave reads only own region)
    const size_t gbase = (m0 + (size_t)wr * 128) * (size_t)N + n0 + (size_t)wc * 64;
    const int sl = lane & 7;
#pragma unroll
    for (int it2 = 0; it2 < 16; ++it2) {
        const int r = it2 * 8 + (lane >> 3);
        short8 vv = *(const short8*)&ep[r * 64 + ((sl ^ (r & 7)) << 3)];
        *(short8*)&C[gbase + (size_t)r * N + sl * 8] = vv;
    }
}

// ---------------- goodness (+optional normalize / +optional argmax) ------------
__global__ __launch_bounds__(256) void good_norm_kernel(
    const u16* __restrict__ x, const float* __restrict__ h,
    float* __restrict__ total, u16* __restrict__ xn,
    int* __restrict__ outp, int mode)
{
    __shared__ __align__(16) u16 hs[10 * 2048];  // 40 KiB
    const int tid = threadIdx.x;
    for (int i = tid; i < 2560; i += 256) {
        const float* hp = h + (size_t)i * 8;
        short8 v;
#pragma unroll
        for (int j = 0; j < 8; ++j) v[j] = (short)f2bf(hp[j]);
        *(short8*)&hs[i * 8] = v;
    }
    __syncthreads();
    const int w = tid >> 6, lane = tid & 63;
    const int row0 = blockIdx.x * 16;
    for (int r = 0; r < 4; ++r) {
        const int row = row0 + w * 4 + r;
        const u16* xr = x + (size_t)row * 2048;
        float xv[32];
        float ss = 0.f;
#pragma unroll
        for (int q = 0; q < 4; ++q) {
            short8 v = *(const short8*)&xr[lane * 8 + q * 512];
#pragma unroll
            for (int j = 0; j < 8; ++j) {
                float f = bf2f((u16)v[j]);
                xv[q * 8 + j] = f;
                ss += f * f;
            }
        }
        float cls[10];
#pragma unroll
        for (int c = 0; c < 10; ++c) {
            float a = 0.f;
            const u16* hc = &hs[c * 2048];
#pragma unroll
            for (int q = 0; q < 4; ++q) {
                short8 hv = *(const short8*)&hc[lane * 8 + q * 512];
#pragma unroll
                for (int j = 0; j < 8; ++j) a += xv[q * 8 + j] * bf2f((u16)hv[j]);
            }
            cls[c] = a;
        }
#pragma unroll
        for (int off = 32; off; off >>= 1) {
#pragma unroll
            for (int c = 0; c < 10; ++c) cls[c] += __shfl_xor(cls[c], off);
        }
        if (mode != 2) {
#pragma unroll
            for (int off = 32; off; off >>= 1) ss += __shfl_xor(ss, off);
            const float scale = 1.f / (sqrtf(ss) + 1e-4f);
            u16* xo = xn + (size_t)row * 2048;
#pragma unroll
            for (int q = 0; q < 4; ++q) {
                short8 v;
#pragma unroll
                for (int j = 0; j < 8; ++j) v[j] = (short)f2bf(xv[q * 8 + j] * scale);
                *(short8*)&xo[lane * 8 + q * 512] = v;
            }
            if (lane == 0) {
                float* trow = total + (size_t)row * 10;
                if (mode == 0) {
#pragma unroll
                    for (int c = 0; c < 10; ++c) trow[c] = cls[c];
                } else {
#pragma unroll
                    for (int c = 0; c < 10; ++c) trow[c] += cls[c];
                }
            }
        } else {
            if (lane == 0) {
                const float* trow = total + (size_t)row * 10;
                float best = -3.4e38f;
                int bi = 0;
#pragma unroll
                for (int c = 0; c < 10; ++c) {
                    float v = trow[c] + cls[c];
                    if (v > best) { best = v; bi = c; }  // strict > : ties -> lowest
                }
                outp[row] = bi;
            }
        }
    }
}

extern "C" void kernel_launch(void* const* d_in, const int* in_sizes, int n_in,
                              void* d_out, int out_size, void* d_ws, size_t ws_size,
                              hipStream_t stream)
{
    const float* x  = (const float*)d_in[0];
    const float* W0 = (const float*)d_in[1];
    const float* b0 = (const float*)d_in[2];
    const float* h0 = (const float*)d_in[3];
    const float* W1 = (const float*)d_in[4];
    const float* b1 = (const float*)d_in[5];
    const float* h1 = (const float*)d_in[6];
    const float* W2 = (const float*)d_in[7];
    const float* b2 = (const float*)d_in[8];
    const float* h2 = (const float*)d_in[9];
    int* out = (int*)d_out;

    const int M = 16384, N = 2048, K0 = 784, Kp0 = 896, D = 2048;

    char* ws = (char*)d_ws;
    size_t off = 0;
    auto alloc = [&](size_t bytes) -> void* {
        void* p = ws + off;
        off += (bytes + 255) & ~(size_t)255;
        return p;
    };
    u16* buf1  = (u16*)alloc((size_t)M * D * 2);   // activations (pre-norm)
    u16* buf2  = (u16*)alloc((size_t)M * D * 2);   // normalized activations; also A0p
    u16* W0p   = (u16*)alloc((size_t)N * Kp0 * 2);
    u16* W1b   = (u16*)alloc((size_t)N * D * 2);
    u16* W2b   = (u16*)alloc((size_t)N * D * 2);
    float* total = (float*)alloc((size_t)M * 10 * 4);
    u16* A0p = buf2;  // 896-stride rows fit inside 2048-stride buffer

    convert_w_kernel<<<2048, 256, 0, stream>>>(W0, W0p, K0, Kp0, (long)N * Kp0);
    convert_w_kernel<<<2048, 256, 0, stream>>>(W1, W1b, D, D, (long)N * D);
    convert_w_kernel<<<2048, 256, 0, stream>>>(W2, W2b, D, D, (long)N * D);

    norm_x0_kernel<<<M, 256, 0, stream>>>(x, A0p, K0, Kp0);

    const int g256 = (M / 256) * (N / 256);  // 512 blocks, %8 == 0
    gemm256_8ph<<<g256, 512, 0, stream>>>(A0p, W0p, b0, buf1, N, Kp0);
    good_norm_kernel<<<M / 16, 256, 0, stream>>>(buf1, h0, total, buf2, nullptr, 0);

    gemm256_8ph<<<g256, 512, 0, stream>>>(buf2, W1b, b1, buf1, N, D);
    good_norm_kernel<<<M / 16, 256, 0, stream>>>(buf1, h1, total, buf2, nullptr, 1);

    gemm256_8ph<<<g256, 512, 0, stream>>>(buf2, W2b, b2, buf1, N, D);
    good_norm_kernel<<<M / 16, 256, 0, stream>>>(buf1, h2, total, nullptr, out, 2);
}

// Round 8
// 684.901 us; speedup vs baseline: 1.1587x; 1.1587x over previous
//
#include <hip/hip_runtime.h>

typedef __attribute__((ext_vector_type(8))) short short8;
typedef __attribute__((ext_vector_type(4))) float f32x4;
typedef unsigned short u16;

#define DEVI static __device__ __forceinline__

DEVI float bf2f(u16 u) {
    unsigned int x = ((unsigned int)u) << 16;
    float f;
    __builtin_memcpy(&f, &x, 4);
    return f;
}
DEVI u16 f2bf(float f) {
    unsigned int x;
    __builtin_memcpy(&x, &f, 4);
    unsigned int r = x + 0x7fffu + ((x >> 16) & 1u);
    return (u16)(r >> 16);
}

// ---------------- W f32 -> bf16 (with K padding to Kp) ----------------
__global__ __launch_bounds__(256) void convert_w_kernel(
    const float* __restrict__ wsrc, u16* __restrict__ wdst,
    int K, int Kp, long total_elems)
{
    long idx = (long)blockIdx.x * 256 + threadIdx.x;
    const long stride = (long)gridDim.x * 256;
    for (; idx < total_elems; idx += stride) {
        long rw = idx / Kp;
        int col = (int)(idx - rw * Kp);
        float v = (col < K) ? wsrc[rw * K + col] : 0.f;
        wdst[idx] = f2bf(v);
    }
}

// ------- row L2-normalize x0 (f32, K cols) -> bf16 (Kp cols, zero pad) -------
__global__ __launch_bounds__(256) void norm_x0_kernel(
    const float* __restrict__ x, u16* __restrict__ outp, int K, int Kp)
{
    const int row = blockIdx.x;
    const float* xr = x + (size_t)row * K;
    float ss = 0.f;
    for (int c = threadIdx.x; c < K; c += 256) { float v = xr[c]; ss += v * v; }
#pragma unroll
    for (int off = 32; off; off >>= 1) ss += __shfl_xor(ss, off);
    __shared__ float red[4];
    if ((threadIdx.x & 63) == 0) red[threadIdx.x >> 6] = ss;
    __syncthreads();
    const float tot = red[0] + red[1] + red[2] + red[3];
    const float scale = 1.f / (sqrtf(tot) + 1e-4f);
    u16* orow = outp + (size_t)row * Kp;
    for (int c = threadIdx.x; c < Kp; c += 256)
        orow[c] = f2bf(c < K ? xr[c] * scale : 0.f);
}

// ============ 256x256 GEMM, m201-style 4-phase/K-tile schedule ============
// Quadrant qm uses A-half qm (tile rows qm*128..+127); qn uses B-half qn.
// Half-tile stream: ph0->Ah0(s+1), ph1->Bh0(s+1), ph2->Bh1(s+1), ph3->Ah1(s+1).
// vmcnt(4) at ph0/ph1/ph3 (2 half-tiles stay in flight; drained ht has
// 3-4 phases slack). Phase: reads; stage; [vmcnt]; barrier; lgkm0;
// sched_barrier; setprio1; 16 MFMA; setprio0; barrier.

#define AS1G const __attribute__((address_space(1))) void*
#define AS3L __attribute__((address_space(3))) void*

#define STAGE_A(s_, h_) do {                                                     \
    const int sd_ = (s_) & 1; const size_t ko_ = (size_t)(s_) << 6;              \
    _Pragma("unroll") for (int i_ = 0; i_ < 2; ++i_)                             \
        __builtin_amdgcn_global_load_lds(                                        \
            (AS1G)(pA + (size_t)((h_) * 128 + i_ * 64) * K + ko_),               \
            (AS3L)&ldsA[sd_ * 16384 + (h_) * 8192 + i_ * 4096 + w * 512],        \
            16, 0, 0);                                                           \
} while (0)

#define STAGE_B(s_, h_) do {                                                     \
    const int sd_ = (s_) & 1; const size_t ko_ = (size_t)(s_) << 6;              \
    _Pragma("unroll") for (int i_ = 0; i_ < 2; ++i_)                             \
        __builtin_amdgcn_global_load_lds(                                        \
            (AS1G)(pB + (size_t)((h_) * 128 + i_ * 64) * K + ko_),               \
            (AS3L)&ldsB[sd_ * 16384 + (h_) * 8192 + i_ * 4096 + w * 512],        \
            16, 0, 0);                                                           \
} while (0)

#define READ_A(qm_)                                                              \
    _Pragma("unroll") for (int i2_ = 0; i2_ < 4; ++i2_)                          \
    _Pragma("unroll") for (int kk_ = 0; kk_ < 2; ++kk_)                          \
        a_[i2_][kk_] = *(const short8*)&ldsA[d * 16384 + (qm_) * 8192 +          \
            (wr * 64 + i2_ * 16 + rsel) * 64 + ((((kk_ << 2) + hi) ^ lsw) << 3)]

#define READ_B(qn_, bb_)                                                         \
    _Pragma("unroll") for (int j2_ = 0; j2_ < 2; ++j2_)                          \
    _Pragma("unroll") for (int kk_ = 0; kk_ < 2; ++kk_)                          \
        bb_[j2_][kk_] = *(const short8*)&ldsB[d * 16384 + (qn_) * 8192 +         \
            (wc * 32 + j2_ * 16 + rsel) * 64 + ((((kk_ << 2) + hi) ^ lsw) << 3)]

#define MFMA_Q(qm_, qn_, bb_)                                                    \
    _Pragma("unroll") for (int i2_ = 0; i2_ < 4; ++i2_)                          \
    _Pragma("unroll") for (int j2_ = 0; j2_ < 2; ++j2_)                          \
    _Pragma("unroll") for (int kk_ = 0; kk_ < 2; ++kk_)                          \
        acc[(qm_) * 4 + i2_][(qn_) * 2 + j2_] =                                  \
            __builtin_amdgcn_mfma_f32_16x16x32_bf16(                             \
                a_[i2_][kk_], bb_[j2_][kk_],                                     \
                acc[(qm_) * 4 + i2_][(qn_) * 2 + j2_], 0, 0, 0)

#define PH_TAIL(mq_)                                                             \
    asm volatile("s_waitcnt lgkmcnt(0)" ::: "memory");                           \
    __builtin_amdgcn_sched_barrier(0);                                           \
    __builtin_amdgcn_s_setprio(1);                                               \
    mq_;                                                                         \
    __builtin_amdgcn_s_setprio(0);                                               \
    __builtin_amdgcn_s_barrier()

__global__ __launch_bounds__(512, 2) void gemm256_m201(
    const u16* __restrict__ A, const u16* __restrict__ W,
    const float* __restrict__ bias, u16* __restrict__ C,
    int N, int K)
{
    __shared__ __align__(16) u16 ldsA[2 * 2 * 128 * 64];  // [dbuf][half][128][64]
    __shared__ __align__(16) u16 ldsB[2 * 2 * 128 * 64];

    const int tid = threadIdx.x;
    const int lane = tid & 63;
    const int w = tid >> 6;               // wave 0..7
    const int wr = w >> 2, wc = w & 3;    // 2M x 4N wave grid
    const int rsel = lane & 15, hi = lane >> 4, lsw = lane & 7;

    // T1: XCD-aware bijective swizzle (grid % 8 == 0)
    int bid = blockIdx.x;
    const int cpx = gridDim.x >> 3;
    bid = (bid & 7) * cpx + (bid >> 3);
    const int ntn = N >> 8;
    const int tm = bid / ntn, tn = bid - tm * ntn;
    const size_t m0 = (size_t)tm << 8, n0 = (size_t)tn << 8;

    const int NS = K >> 6;

    // staging address base: thread t covers dest row (i*64 + t>>3), slot t&7,
    // source col-slot pre-swizzled (T2 involution: src slot = dst ^ (row&7)).
    const int srow = tid >> 3;
    const int scol = ((tid & 7) ^ (srow & 7)) << 3;
    const u16* pA = A + (m0 + srow) * (size_t)K + scol;
    const u16* pB = W + (n0 + srow) * (size_t)K + scol;

    f32x4 acc[8][4] = {};
    short8 a_[4][2], bA[2][2], bB[2][2];

    // prologue: full tile 0, in consumption order; keep Bh1,Ah1 in flight.
    STAGE_A(0, 0); STAGE_B(0, 0); STAGE_B(0, 1); STAGE_A(0, 1);
    asm volatile("s_waitcnt vmcnt(4)" ::: "memory");
    __builtin_amdgcn_s_barrier();
    __builtin_amdgcn_sched_barrier(0);

    for (int s = 0; s < NS; ++s) {
        const int d = s & 1;
        const bool pf = (s + 1 < NS);

        // ---- ph0: quadrant (0,0); needs Ah0,Bh0 (drained @ph3 prev) ----
        READ_A(0);
        READ_B(0, bA);
        if (pf) {
            STAGE_A(s + 1, 0);
            asm volatile("s_waitcnt vmcnt(4)" ::: "memory");  // drain Bh1(s)
        } else {
            asm volatile("s_waitcnt vmcnt(2)" ::: "memory");
        }
        __builtin_amdgcn_s_barrier();
        PH_TAIL(MFMA_Q(0, 0, bA));

        // ---- ph1: quadrant (0,1); needs Bh1(s) ----
        READ_B(1, bB);
        if (pf) {
            STAGE_B(s + 1, 0);
            asm volatile("s_waitcnt vmcnt(4)" ::: "memory");  // drain Ah1(s)
        } else {
            asm volatile("s_waitcnt vmcnt(0)" ::: "memory");
        }
        __builtin_amdgcn_s_barrier();
        PH_TAIL(MFMA_Q(0, 1, bB));

        // ---- ph2: quadrant (1,0); needs Ah1(s) ----
        READ_A(1);
        if (pf) STAGE_B(s + 1, 1);
        __builtin_amdgcn_s_barrier();
        PH_TAIL(MFMA_Q(1, 0, bA));

        // ---- ph3: quadrant (1,1); no new reads ----
        if (pf) {
            STAGE_A(s + 1, 1);
            asm volatile("s_waitcnt vmcnt(4)" ::: "memory");  // drain Ah0,Bh0(s+1)
        }
        __builtin_amdgcn_s_barrier();
        __builtin_amdgcn_sched_barrier(0);   // pin next-phase reads below rendezvous
        __builtin_amdgcn_s_setprio(1);
        MFMA_Q(1, 1, bB);
        __builtin_amdgcn_s_setprio(0);
        __builtin_amdgcn_s_barrier();
    }

    // ---- epilogue: bias+relu, repack via own 16KB LDS region, coalesced ----
    // local row lr = qm*64 + i2*16 + hi*4 + rg  -> global m0 + qm*128 + wr*64 + ...
    // local col lc = qn*32 + j2*16 + rsel       -> global n0 + qn*128 + wc*32 + ...
    u16* ep = (w < 4) ? &ldsA[w * 8192] : &ldsB[(w - 4) * 8192];
#pragma unroll
    for (int j = 0; j < 4; ++j) {
        const float bv = bias[n0 + (j >> 1) * 128 + wc * 32 + (j & 1) * 16 + rsel];
        const int lc = (j >> 1) * 32 + (j & 1) * 16 + rsel;
        const int slot = lc >> 3, cb = lc & 7;
#pragma unroll
        for (int i = 0; i < 8; ++i) {
            const int lrb = (i >> 2) * 64 + (i & 3) * 16 + hi * 4;
#pragma unroll
            for (int rg = 0; rg < 4; ++rg) {
                const int lr = lrb + rg;
                float v = acc[i][j][rg] + bv;
                v = v > 0.f ? v : 0.f;
                ep[lr * 64 + ((slot ^ (lr & 7)) << 3) + cb] = f2bf(v);
            }
        }
    }
    asm volatile("s_waitcnt lgkmcnt(0)" ::: "memory");  // own region only
    const int sl = lane & 7;
#pragma unroll
    for (int it2 = 0; it2 < 16; ++it2) {
        const int r = it2 * 8 + (lane >> 3);
        short8 vv = *(const short8*)&ep[r * 64 + ((sl ^ (r & 7)) << 3)];
        const size_t gr = m0 + (size_t)((r >> 6) * 128 + wr * 64 + (r & 63));
        const size_t gc = n0 + (size_t)((sl >> 2) * 128 + wc * 32 + (sl & 3) * 8);
        *(short8*)&C[gr * (size_t)N + gc] = vv;
    }
}

// ---------------- goodness (+optional normalize / +optional argmax) ------------
__global__ __launch_bounds__(256) void good_norm_kernel(
    const u16* __restrict__ x, const float* __restrict__ h,
    float* __restrict__ total, u16* __restrict__ xn,
    int* __restrict__ outp, int mode)
{
    __shared__ __align__(16) u16 hs[10 * 2048];  // 40 KiB
    const int tid = threadIdx.x;
    for (int i = tid; i < 2560; i += 256) {
        const float* hp = h + (size_t)i * 8;
        short8 v;
#pragma unroll
        for (int j = 0; j < 8; ++j) v[j] = (short)f2bf(hp[j]);
        *(short8*)&hs[i * 8] = v;
    }
    __syncthreads();
    const int w = tid >> 6, lane = tid & 63;
    const int row0 = blockIdx.x * 16;
    for (int r = 0; r < 4; ++r) {
        const int row = row0 + w * 4 + r;
        const u16* xr = x + (size_t)row * 2048;
        float xv[32];
        float ss = 0.f;
#pragma unroll
        for (int q = 0; q < 4; ++q) {
            short8 v = *(const short8*)&xr[lane * 8 + q * 512];
#pragma unroll
            for (int j = 0; j < 8; ++j) {
                float f = bf2f((u16)v[j]);
                xv[q * 8 + j] = f;
                ss += f * f;
            }
        }
        float cls[10];
#pragma unroll
        for (int c = 0; c < 10; ++c) {
            float a = 0.f;
            const u16* hc = &hs[c * 2048];
#pragma unroll
            for (int q = 0; q < 4; ++q) {
                short8 hv = *(const short8*)&hc[lane * 8 + q * 512];
#pragma unroll
                for (int j = 0; j < 8; ++j) a += xv[q * 8 + j] * bf2f((u16)hv[j]);
            }
            cls[c] = a;
        }
#pragma unroll
        for (int off = 32; off; off >>= 1) {
#pragma unroll
            for (int c = 0; c < 10; ++c) cls[c] += __shfl_xor(cls[c], off);
        }
        if (mode != 2) {
#pragma unroll
            for (int off = 32; off; off >>= 1) ss += __shfl_xor(ss, off);
            const float scale = 1.f / (sqrtf(ss) + 1e-4f);
            u16* xo = xn + (size_t)row * 2048;
#pragma unroll
            for (int q = 0; q < 4; ++q) {
                short8 v;
#pragma unroll
                for (int j = 0; j < 8; ++j) v[j] = (short)f2bf(xv[q * 8 + j] * scale);
                *(short8*)&xo[lane * 8 + q * 512] = v;
            }
            if (lane == 0) {
                float* trow = total + (size_t)row * 10;
                if (mode == 0) {
#pragma unroll
                    for (int c = 0; c < 10; ++c) trow[c] = cls[c];
                } else {
#pragma unroll
                    for (int c = 0; c < 10; ++c) trow[c] += cls[c];
                }
            }
        } else {
            if (lane == 0) {
                const float* trow = total + (size_t)row * 10;
                float best = -3.4e38f;
                int bi = 0;
#pragma unroll
                for (int c = 0; c < 10; ++c) {
                    float v = trow[c] + cls[c];
                    if (v > best) { best = v; bi = c; }  // strict > : ties -> lowest
                }
                outp[row] = bi;
            }
        }
    }
}

extern "C" void kernel_launch(void* const* d_in, const int* in_sizes, int n_in,
                              void* d_out, int out_size, void* d_ws, size_t ws_size,
                              hipStream_t stream)
{
    const float* x  = (const float*)d_in[0];
    const float* W0 = (const float*)d_in[1];
    const float* b0 = (const float*)d_in[2];
    const float* h0 = (const float*)d_in[3];
    const float* W1 = (const float*)d_in[4];
    const float* b1 = (const float*)d_in[5];
    const float* h1 = (const float*)d_in[6];
    const float* W2 = (const float*)d_in[7];
    const float* b2 = (const float*)d_in[8];
    const float* h2 = (const float*)d_in[9];
    int* out = (int*)d_out;

    const int M = 16384, N = 2048, K0 = 784, Kp0 = 896, D = 2048;

    char* ws = (char*)d_ws;
    size_t off = 0;
    auto alloc = [&](size_t bytes) -> void* {
        void* p = ws + off;
        off += (bytes + 255) & ~(size_t)255;
        return p;
    };
    u16* buf1  = (u16*)alloc((size_t)M * D * 2);   // activations (pre-norm)
    u16* buf2  = (u16*)alloc((size_t)M * D * 2);   // normalized activations; also A0p
    u16* W0p   = (u16*)alloc((size_t)N * Kp0 * 2);
    u16* W1b   = (u16*)alloc((size_t)N * D * 2);
    u16* W2b   = (u16*)alloc((size_t)N * D * 2);
    float* total = (float*)alloc((size_t)M * 10 * 4);
    u16* A0p = buf2;  // 896-stride rows fit inside 2048-stride buffer

    convert_w_kernel<<<2048, 256, 0, stream>>>(W0, W0p, K0, Kp0, (long)N * Kp0);
    convert_w_kernel<<<2048, 256, 0, stream>>>(W1, W1b, D, D, (long)N * D);
    convert_w_kernel<<<2048, 256, 0, stream>>>(W2, W2b, D, D, (long)N * D);

    norm_x0_kernel<<<M, 256, 0, stream>>>(x, A0p, K0, Kp0);

    const int g256 = (M / 256) * (N / 256);  // 512 blocks, %8 == 0
    gemm256_m201<<<g256, 512, 0, stream>>>(A0p, W0p, b0, buf1, N, Kp0);
    good_norm_kernel<<<M / 16, 256, 0, stream>>>(buf1, h0, total, buf2, nullptr, 0);

    gemm256_m201<<<g256, 512, 0, stream>>>(buf2, W1b, b1, buf1, N, D);
    good_norm_kernel<<<M / 16, 256, 0, stream>>>(buf1, h1, total, buf2, nullptr, 1);

    gemm256_m201<<<g256, 512, 0, stream>>>(buf2, W2b, b2, buf1, N, D);
    good_norm_kernel<<<M / 16, 256, 0, stream>>>(buf1, h2, total, nullptr, out, 2);
}